// Round 15
// baseline (158.905 us; speedup 1.0000x reference)
//
#include <hip/hip_runtime.h>
#include <hip/hip_bf16.h>

#define BB 8
#define SS 4096
#define DD 1024
#define NN 64
#define ROWS (BB * SS)          // 32768
#define GLD 256                 // 4 gates * 64
#define NCHUNK 256              // chunks per sequence
#define CLEN 16                 // steps per chunk (NCHUNK*CLEN == SS)

typedef _Float16 f16;
using f16x8 = __attribute__((ext_vector_type(8))) _Float16;
using f32x4 = __attribute__((ext_vector_type(4))) float;

__device__ __forceinline__ void async16(void* lds, const void* g) {
    __builtin_amdgcn_global_load_lds(
        (const __attribute__((address_space(1))) unsigned int*)g,
        (__attribute__((address_space(3))) unsigned int*)lds, 16, 0, 0);
}

// ---------------- prep: W' = ln_w ⊙ W packed per-step images; Wp -> fp16; bias folds ----------------
// Wpk byte layout: [s(32)][bn(2)][cb(8)][lane(64)][16B]
//   element = W'[bn*128 + cb*16 + (l&15)][s*32 + (l>>4)*8 + e]
__global__ __launch_bounds__(256) void prep_all(const float* __restrict__ Wi, const float* __restrict__ bi,
                                                const float* __restrict__ Wf, const float* __restrict__ bfv,
                                                const float* __restrict__ Wz, const float* __restrict__ bz,
                                                const float* __restrict__ Wo, const float* __restrict__ bo,
                                                const float* __restrict__ Wp,
                                                const float* __restrict__ ln_w, const float* __restrict__ ln_b,
                                                f16* __restrict__ Wpk, f16* __restrict__ Wpf,
                                                float* __restrict__ ball, float* __restrict__ e_all) {
    if (blockIdx.x < 384) {
        int i = blockIdx.x * 256 + threadIdx.x;
        if (i < 32768) {
            int l = i & 63, cb = (i >> 6) & 7, bn = (i >> 9) & 1, s = i >> 10;
            int col = bn * 128 + cb * 16 + (l & 15);
            int k = s * 32 + (l >> 4) * 8;
            int g = col >> 6, rem = col & 63;
            const float* W = (g == 0) ? Wi : (g == 1) ? Wf : (g == 2) ? Wz : Wo;
            const float* src = W + rem * 1024 + k;
            const float* lwp = ln_w + k;
            f16x8 v;
            #pragma unroll
            for (int e = 0; e < 8; ++e) v[e] = (f16)(src[e] * lwp[e]);
            *reinterpret_cast<f16x8*>(Wpk + (size_t)s * 8192 + bn * 4096 + cb * 512 + l * 8) = v;
        } else if (i < 32768 + 65536) {
            int j = i - 32768;
            Wpf[j] = (f16)Wp[j];
        }
    } else {
        int j = (blockIdx.x - 384) * 4 + (threadIdx.x >> 6);
        int lane = threadIdx.x & 63;
        int g = j >> 6, rem = j & 63;
        const float* W  = (g == 0) ? Wi : (g == 1) ? Wf : (g == 2) ? Wz : Wo;
        const float* bs = (g == 0) ? bi : (g == 1) ? bfv : (g == 2) ? bz : bo;
        const float* row = W + rem * 1024;
        float d = 0.0f, e = 0.0f;
        #pragma unroll
        for (int t = 0; t < 16; ++t) {
            int k = lane + 64 * t;
            float w = row[k];
            e += ln_w[k] * w;
            d += ln_b[k] * w;
        }
        #pragma unroll
        for (int off = 1; off < 64; off <<= 1) {
            e += __shfl_xor(e, off);
            d += __shfl_xor(d, off);
        }
        if (lane == 0) { ball[j] = bs[rem] + d; e_all[j] = e; }
    }
}

// ---------------- fused LN + gate GEMM: m97-exact (both operands via global_load_lds) ----------------
// 256 thr = 4 waves (2M x 2N). Tile 128 x 128, BK=32, 32 steps. Grid 512 (bmi, bn) = 2 blocks/CU.
// Per step: stage 16KB x(fp32, source-swizzled) + 8KB W(f16) async -> compute -> __syncthreads.
// fp32->f16 conversion + LN-stats accumulation happen at fragment-load time (off staging path).
__global__ __launch_bounds__(256, 2) void gate_gemm(const float* __restrict__ x,
                                                    const f16* __restrict__ Wpk,
                                                    const float* __restrict__ ball,
                                                    const float* __restrict__ e_all,
                                                    float* __restrict__ gates) {
    int bmi = blockIdx.x >> 1, bn = blockIdx.x & 1;
    int bm = bmi * 128;
    int tid = threadIdx.x;
    int wid = tid >> 6, lane = tid & 63;
    int wm = wid >> 1, wn = wid & 1;
    int lrow = lane & 15, lkg = lane >> 4;

    __shared__ __align__(16) char lds[2][24576];   // [0,16K) x fp32 (swizzled), [16K,24K) W f16
    __shared__ float2 stats_lds[128];

    // staging: 6 async16 per thread; d = wid*6144 + i*1024 + lane*16
    auto stage = [&](int s, int buf) {
        #pragma unroll
        for (int i = 0; i < 6; ++i) {
            int d = wid * 6144 + i * 1024 + lane * 16;
            char* dst = &lds[buf][d];
            const char* src;
            if (d < 16384) {
                int row = d >> 7;
                int col16 = ((d >> 4) & 7) ^ (row & 7);
                src = (const char*)x + (size_t)(bm + row) * 4096 + s * 128 + col16 * 16;
            } else {
                src = (const char*)Wpk + (size_t)s * 16384 + bn * 8192 + (d - 16384);
            }
            async16(dst, src);
        }
    };

    f32x4 acc[4][4] = {};
    float s1[4] = {}, s2[4] = {};
    auto compute = [&](int buf) {
        f16x8 a[4];
        #pragma unroll
        for (int mf = 0; mf < 4; ++mf) {
            int row = wm * 64 + mf * 16 + lrow;
            const char* rb_ = &lds[buf][row * 128];
            int r7 = row & 7;
            float4 q0 = *reinterpret_cast<const float4*>(rb_ + (((2 * lkg) ^ r7) << 4));
            float4 q1 = *reinterpret_cast<const float4*>(rb_ + (((2 * lkg + 1) ^ r7) << 4));
            if (wn == 0) {
                s1[mf] += q0.x + q0.y + q0.z + q0.w + q1.x + q1.y + q1.z + q1.w;
                s2[mf] += q0.x * q0.x + q0.y * q0.y + q0.z * q0.z + q0.w * q0.w
                        + q1.x * q1.x + q1.y * q1.y + q1.z * q1.z + q1.w * q1.w;
            }
            f16x8 t;
            t[0] = (f16)q0.x; t[1] = (f16)q0.y; t[2] = (f16)q0.z; t[3] = (f16)q0.w;
            t[4] = (f16)q1.x; t[5] = (f16)q1.y; t[6] = (f16)q1.z; t[7] = (f16)q1.w;
            a[mf] = t;
        }
        #pragma unroll
        for (int nf = 0; nf < 4; ++nf) {
            int cb = wn * 4 + nf;
            f16x8 w = *reinterpret_cast<const f16x8*>(&lds[buf][16384 + cb * 1024 + lane * 16]);
            #pragma unroll
            for (int mf = 0; mf < 4; ++mf)
                acc[mf][nf] = __builtin_amdgcn_mfma_f32_16x16x32_f16(a[mf], w, acc[mf][nf], 0, 0, 0);
        }
    };

    // m97 main loop: stage ahead, compute, full-drain barrier
    stage(0, 0);
    __syncthreads();
    for (int s = 0; s < 32; ++s) {
        int buf = s & 1;
        if (s < 31) stage(s + 1, buf ^ 1);
        compute(buf);
        __syncthreads();
    }

    // stats: per-mf reduce over lkg (lanes differing in bits 4,5)
    if (wn == 0) {
        #pragma unroll
        for (int mf = 0; mf < 4; ++mf) {
            float a1 = s1[mf], a2 = s2[mf];
            a1 += __shfl_xor(a1, 16); a2 += __shfl_xor(a2, 16);
            a1 += __shfl_xor(a1, 32); a2 += __shfl_xor(a2, 32);
            if (lane < 16) {
                int row = wm * 64 + mf * 16 + lrow;
                float mu = a1 * (1.0f / DD);
                float var = a2 * (1.0f / DD) - mu * mu;
                float rsd = rsqrtf(var + 1e-5f);
                float2 st; st.x = mu * rsd; st.y = rsd;
                stats_lds[row] = st;
            }
        }
    }
    __syncthreads();

    // epilogue: LN fold + activations -> gates
    int gidx = bn * 2 + wn;                 // gate index (wave-uniform)
    int rb = (lane >> 4) * 4;
    #pragma unroll
    for (int mf = 0; mf < 4; ++mf) {
        #pragma unroll
        for (int nf = 0; nf < 4; ++nf) {
            int col = bn * 128 + wn * 64 + nf * 16 + lrow;
            float bc = ball[col];
            float ec = e_all[col];
            #pragma unroll
            for (int r = 0; r < 4; ++r) {
                int rl = wm * 64 + mf * 16 + rb + r;
                float2 st = stats_lds[rl];
                float v = acc[mf][nf][r] * st.y + bc - st.x * ec;
                float res;
                if (gidx < 2)           res = fminf(fmaxf(v, -20.0f), 20.0f);
                else if (gidx == 2)     res = tanhf(v);
                else                    res = 1.0f / (1.0f + expf(-v));
                gates[(size_t)(bm + rl) * GLD + col] = res;
            }
        }
    }
}

// ---------------- scan phase A: per-chunk summaries -> interleaved float4 ----------------
__global__ __launch_bounds__(256) void scan_a(const float* __restrict__ gates,
                                              float4* __restrict__ s4) {
    int w = blockIdx.x * 4 + (threadIdx.x >> 6);
    int lane = threadIdx.x & 63;
    int b = w >> 8, k = w & (NCHUNK - 1);
    int t0 = k * CLEN;
    const float* gp = gates + ((size_t)(b * SS + t0)) * GLD + lane;
    float Lf = 0.0f, m = -1e30f, c = 0.0f;
    for (int t = 0; t < CLEN; ++t) {
        float li = gp[0], lf = gp[64], z = gp[128];
        gp += GLD;
        Lf += lf;
        float ma = m + lf;
        float mn = fmaxf(ma, li);
        c = expf(ma - mn) * c + expf(li - mn) * z;
        m = mn;
    }
    float4 v; v.x = Lf; v.y = m; v.z = c; v.w = 0.0f;
    s4[(size_t)(b * NCHUNK + k) * 64 + lane] = v;
}

// ---------------- scan phase B: sequential compose, prefetch-16 pipeline ----------------
__global__ __launch_bounds__(64) void scan_b(const float4* __restrict__ s4,
                                             float2* __restrict__ c2) {
    int b = blockIdx.x;
    int n = threadIdx.x;
    size_t base = (size_t)b * NCHUNK * 64 + n;
    float c = 0.0f, m = 0.0f;   // reference init: c0=0, m0=0
    float4 cur[16];
    #pragma unroll
    for (int d = 0; d < 16; ++d) cur[d] = s4[base + (size_t)d * 64];
    for (int kb = 0; kb < NCHUNK; kb += 16) {
        float4 nxt[16];
        if (kb + 16 < NCHUNK) {
            #pragma unroll
            for (int d = 0; d < 16; ++d) nxt[d] = s4[base + (size_t)(kb + 16 + d) * 64];
        }
        #pragma unroll
        for (int d = 0; d < 16; ++d) {
            float2 ci; ci.x = m; ci.y = c;
            c2[base + (size_t)(kb + d) * 64] = ci;
            float4 v = cur[d];
            float ma = m + v.x;
            float mo = fmaxf(ma, v.y);
            c = expf(ma - mo) * c + expf(v.y - mo) * v.z;
            m = mo;
        }
        #pragma unroll
        for (int d = 0; d < 16; ++d) cur[d] = nxt[d];
    }
}

// ---------------- scan phase C: replay chunks, emit h (fp16) ----------------
__global__ __launch_bounds__(256) void scan_c(const float* __restrict__ gates,
                                              const float2* __restrict__ c2,
                                              f16* __restrict__ h) {
    int w = blockIdx.x * 4 + (threadIdx.x >> 6);
    int lane = threadIdx.x & 63;
    int b = w >> 8, k = w & (NCHUNK - 1);
    int t0 = k * CLEN;
    float2 ci = c2[(size_t)(b * NCHUNK + k) * 64 + lane];
    float m = ci.x, c = ci.y;
    const float* gp = gates + ((size_t)(b * SS + t0)) * GLD + lane;
    f16* hp = h + ((size_t)(b * SS + t0)) * NN + lane;
    for (int t = 0; t < CLEN; ++t) {
        float li = gp[0], lf = gp[64], z = gp[128], o = gp[192];
        gp += GLD;
        float ma = m + lf;
        float mn = fmaxf(ma, li);
        c = expf(ma - mn) * c + expf(li - mn) * z;
        m = mn;
        *hp = (f16)(o * tanhf(c));
        hp += NN;
    }
}

// ---------------- output projection: h(32768x64) * Wpf^T(1024x64) + bp -> out ----------------
__global__ __launch_bounds__(256) void out_gemm(const f16* __restrict__ h,
                                                const f16* __restrict__ Wpf,
                                                const float* __restrict__ bp,
                                                float* __restrict__ out) {
    int tid = threadIdx.x, wid = tid >> 6, lane = tid & 63;
    int r0 = (blockIdx.x >> 1) * 32;
    int c0 = (blockIdx.x & 1) * 512 + wid * 128;
    int lrow = lane & 15, lk = (lane >> 4) * 8;

    f32x4 acc[2][8] = {};
    #pragma unroll
    for (int ks = 0; ks < 2; ++ks) {
        int kk = ks * 32;
        f16x8 a[2], bfr[8];
        #pragma unroll
        for (int mf = 0; mf < 2; ++mf)
            a[mf] = *reinterpret_cast<const f16x8*>(h + (size_t)(r0 + mf * 16 + lrow) * NN + kk + lk);
        #pragma unroll
        for (int nf = 0; nf < 8; ++nf)
            bfr[nf] = *reinterpret_cast<const f16x8*>(Wpf + (size_t)(c0 + nf * 16 + lrow) * NN + kk + lk);
        #pragma unroll
        for (int mf = 0; mf < 2; ++mf)
            #pragma unroll
            for (int nf = 0; nf < 8; ++nf)
                acc[mf][nf] = __builtin_amdgcn_mfma_f32_16x16x32_f16(a[mf], bfr[nf], acc[mf][nf], 0, 0, 0);
    }
    int rb = (lane >> 4) * 4;
    #pragma unroll
    for (int nf = 0; nf < 8; ++nf) {
        int col = c0 + nf * 16 + (lane & 15);
        float bias = bp[col];
        #pragma unroll
        for (int mf = 0; mf < 2; ++mf) {
            #pragma unroll
            for (int r = 0; r < 4; ++r) {
                int row = r0 + mf * 16 + rb + r;
                out[(size_t)row * DD + col] = acc[mf][nf][r] + bias;
            }
        }
    }
}

extern "C" void kernel_launch(void* const* d_in, const int* in_sizes, int n_in,
                              void* d_out, int out_size, void* d_ws, size_t ws_size,
                              hipStream_t stream) {
    const float* x    = (const float*)d_in[0];
    const float* ln_w = (const float*)d_in[1];
    const float* ln_b = (const float*)d_in[2];
    const float* Wi   = (const float*)d_in[3];
    const float* bi   = (const float*)d_in[4];
    const float* Wf   = (const float*)d_in[5];
    const float* bfv  = (const float*)d_in[6];
    const float* Wz   = (const float*)d_in[7];
    const float* bz   = (const float*)d_in[8];
    const float* Wo   = (const float*)d_in[9];
    const float* bo   = (const float*)d_in[10];
    const float* Wp   = (const float*)d_in[11];
    const float* bp   = (const float*)d_in[12];
    float* out = (float*)d_out;

    // All scratch in d_ws (~42 MB; ws is ~512 MB). d_out written only by out_gemm.
    char* w = (char*)d_ws;
    float* gates = (float*)w;  w += (size_t)ROWS * GLD * 4;          // 33,554,432
    float4* s4   = (float4*)w; w += (size_t)BB * NCHUNK * 64 * 16;   // 2,097,152
    float2* c2   = (float2*)w; w += (size_t)BB * NCHUNK * 64 * 8;    // 1,048,576
    f16* h       = (f16*)w;    w += (size_t)ROWS * NN * 2;           // 4,194,304
    f16* Wpk     = (f16*)w;    w += 32 * 8192 * 2;                   // 524,288
    f16* Wpf     = (f16*)w;    w += 1024 * 64 * 2;                   // 131,072
    float* ball  = (float*)w;  w += 256 * 4;                         // 1,024
    float* e_all = (float*)w;  w += 256 * 4;                         // 1,024

    prep_all<<<448, 256, 0, stream>>>(Wi, bi, Wf, bfv, Wz, bz, Wo, bo, Wp,
                                      ln_w, ln_b, Wpk, Wpf, ball, e_all);
    gate_gemm<<<512, 256, 0, stream>>>(x, Wpk, ball, e_all, gates);
    scan_a<<<(BB * NCHUNK) / 4, 256, 0, stream>>>(gates, s4);
    scan_b<<<BB, 64, 0, stream>>>(s4, c2);
    scan_c<<<(BB * NCHUNK) / 4, 256, 0, stream>>>(gates, c2, h);
    out_gemm<<<(ROWS / 32) * 2, 256, 0, stream>>>(h, Wpf, bp, out);
}

// Round 16
// 148.713 us; speedup vs baseline: 1.0685x; 1.0685x over previous
//
#include <hip/hip_runtime.h>
#include <hip/hip_bf16.h>

#define BB 8
#define SS 4096
#define DD 1024
#define NN 64
#define ROWS (BB * SS)          // 32768
#define GLD 256                 // 4 gates * 64
#define NCHUNK 256              // chunks per sequence
#define CLEN 16                 // steps per chunk (NCHUNK*CLEN == SS)

typedef _Float16 f16;
using f16x8 = __attribute__((ext_vector_type(8))) _Float16;
using f32x4 = __attribute__((ext_vector_type(4))) float;

__device__ __forceinline__ void async16(void* lds, const void* g) {
    __builtin_amdgcn_global_load_lds(
        (const __attribute__((address_space(1))) unsigned int*)g,
        (__attribute__((address_space(3))) unsigned int*)lds, 16, 0, 0);
}

// ---------------- prep: W' = ln_w ⊙ W packed per-step images; Wp -> fp16; bias folds ----------------
// Wpk byte layout: [s(32)][bn(2)][cb(8)][lane(64)][16B]
//   element = W'[bn*128 + cb*16 + (l&15)][s*32 + (l>>4)*8 + e]
__global__ __launch_bounds__(256) void prep_all(const float* __restrict__ Wi, const float* __restrict__ bi,
                                                const float* __restrict__ Wf, const float* __restrict__ bfv,
                                                const float* __restrict__ Wz, const float* __restrict__ bz,
                                                const float* __restrict__ Wo, const float* __restrict__ bo,
                                                const float* __restrict__ Wp,
                                                const float* __restrict__ ln_w, const float* __restrict__ ln_b,
                                                f16* __restrict__ Wpk, f16* __restrict__ Wpf,
                                                float* __restrict__ ball, float* __restrict__ e_all) {
    if (blockIdx.x < 384) {
        int i = blockIdx.x * 256 + threadIdx.x;
        if (i < 32768) {
            int l = i & 63, cb = (i >> 6) & 7, bn = (i >> 9) & 1, s = i >> 10;
            int col = bn * 128 + cb * 16 + (l & 15);
            int k = s * 32 + (l >> 4) * 8;
            int g = col >> 6, rem = col & 63;
            const float* W = (g == 0) ? Wi : (g == 1) ? Wf : (g == 2) ? Wz : Wo;
            const float* src = W + rem * 1024 + k;
            const float* lwp = ln_w + k;
            f16x8 v;
            #pragma unroll
            for (int e = 0; e < 8; ++e) v[e] = (f16)(src[e] * lwp[e]);
            *reinterpret_cast<f16x8*>(Wpk + (size_t)s * 8192 + bn * 4096 + cb * 512 + l * 8) = v;
        } else if (i < 32768 + 65536) {
            int j = i - 32768;
            Wpf[j] = (f16)Wp[j];
        }
    } else {
        int j = (blockIdx.x - 384) * 4 + (threadIdx.x >> 6);
        int lane = threadIdx.x & 63;
        int g = j >> 6, rem = j & 63;
        const float* W  = (g == 0) ? Wi : (g == 1) ? Wf : (g == 2) ? Wz : Wo;
        const float* bs = (g == 0) ? bi : (g == 1) ? bfv : (g == 2) ? bz : bo;
        const float* row = W + rem * 1024;
        float d = 0.0f, e = 0.0f;
        #pragma unroll
        for (int t = 0; t < 16; ++t) {
            int k = lane + 64 * t;
            float w = row[k];
            e += ln_w[k] * w;
            d += ln_b[k] * w;
        }
        #pragma unroll
        for (int off = 1; off < 64; off <<= 1) {
            e += __shfl_xor(e, off);
            d += __shfl_xor(d, off);
        }
        if (lane == 0) { ball[j] = bs[rem] + d; e_all[j] = e; }
    }
}

// ---------------- fused LN + gate GEMM: async-staged, 4 blocks/CU ----------------
// 256 thr = 4 waves (wave = 16 rows). Tile 64 x 128, BK=32, 32 steps.
// Grid 1024 (512 bmi x 2 bn) = 4 blocks/CU, 16 waves/CU.
// Per step: stage 8KB x(fp32, source-swizzled) + 8KB W(f16) via global_load_lds -> compute -> barrier.
// fp32->f16 conversion + LN-stats accumulation at fragment-load time.
__global__ __launch_bounds__(256, 4) void gate_gemm(const float* __restrict__ x,
                                                    const f16* __restrict__ Wpk,
                                                    const float* __restrict__ ball,
                                                    const float* __restrict__ e_all,
                                                    float* __restrict__ gates) {
    int bmi = blockIdx.x >> 1, bn = blockIdx.x & 1;
    int bm = bmi * 64;
    int tid = threadIdx.x;
    int wid = tid >> 6, lane = tid & 63;
    int lrow = lane & 15, lkg = lane >> 4;
    int wrow = wid * 16 + lrow;              // this lane's x row within tile

    __shared__ __align__(16) char lds[2][16384];   // [0,8K) x fp32 swizzled, [8K,16K) W f16
    __shared__ float2 stats_lds[64];

    // staging: 4 async16 per thread; d = wid*4096 + i*1024 + lane*16
    auto stage = [&](int s, int buf) {
        #pragma unroll
        for (int i = 0; i < 4; ++i) {
            int d = wid * 4096 + i * 1024 + lane * 16;
            char* dst = &lds[buf][d];
            const char* src;
            if (d < 8192) {
                int row = d >> 7;
                int col16 = ((d >> 4) & 7) ^ (row & 7);
                src = (const char*)x + (size_t)(bm + row) * 4096 + s * 128 + col16 * 16;
            } else {
                src = (const char*)Wpk + (size_t)s * 16384 + bn * 8192 + (d - 8192);
            }
            async16(dst, src);
        }
    };

    f32x4 acc[8] = {};
    float s1 = 0.0f, s2 = 0.0f;
    auto compute = [&](int buf) {
        const char* rb_ = &lds[buf][wrow * 128];
        int r7 = wrow & 7;
        float4 q0 = *reinterpret_cast<const float4*>(rb_ + (((2 * lkg) ^ r7) << 4));
        float4 q1 = *reinterpret_cast<const float4*>(rb_ + (((2 * lkg + 1) ^ r7) << 4));
        s1 += q0.x + q0.y + q0.z + q0.w + q1.x + q1.y + q1.z + q1.w;
        s2 += q0.x * q0.x + q0.y * q0.y + q0.z * q0.z + q0.w * q0.w
            + q1.x * q1.x + q1.y * q1.y + q1.z * q1.z + q1.w * q1.w;
        f16x8 a;
        a[0] = (f16)q0.x; a[1] = (f16)q0.y; a[2] = (f16)q0.z; a[3] = (f16)q0.w;
        a[4] = (f16)q1.x; a[5] = (f16)q1.y; a[6] = (f16)q1.z; a[7] = (f16)q1.w;
        #pragma unroll
        for (int nf = 0; nf < 8; ++nf) {
            f16x8 w = *reinterpret_cast<const f16x8*>(&lds[buf][8192 + nf * 1024 + lane * 16]);
            acc[nf] = __builtin_amdgcn_mfma_f32_16x16x32_f16(a, w, acc[nf], 0, 0, 0);
        }
    };

    // main loop: stage ahead, compute, full-drain barrier (m97 pattern)
    stage(0, 0);
    __syncthreads();
    for (int s = 0; s < 32; ++s) {
        int buf = s & 1;
        if (s < 31) stage(s + 1, buf ^ 1);
        compute(buf);
        __syncthreads();
    }

    // stats: reduce over lkg (lanes differing in bits 4,5); lanes 0-15 hold rows wid*16+lrow
    {
        float a1 = s1, a2 = s2;
        a1 += __shfl_xor(a1, 16); a2 += __shfl_xor(a2, 16);
        a1 += __shfl_xor(a1, 32); a2 += __shfl_xor(a2, 32);
        if (lane < 16) {
            float mu = a1 * (1.0f / DD);
            float var = a2 * (1.0f / DD) - mu * mu;
            float rsd = rsqrtf(var + 1e-5f);
            float2 st; st.x = mu * rsd; st.y = rsd;
            stats_lds[wrow] = st;
        }
    }
    __syncthreads();

    // epilogue: LN fold + activations -> gates
    int rb = (lane >> 4) * 4;
    #pragma unroll
    for (int nf = 0; nf < 8; ++nf) {
        int col = bn * 128 + nf * 16 + lrow;
        int gidx = bn * 2 + (nf >> 2);       // gate index (wave-uniform per nf)
        float bc = ball[col];
        float ec = e_all[col];
        #pragma unroll
        for (int r = 0; r < 4; ++r) {
            int rl = wid * 16 + rb + r;
            float2 st = stats_lds[rl];
            float v = acc[nf][r] * st.y + bc - st.x * ec;
            float res;
            if (gidx < 2)           res = fminf(fmaxf(v, -20.0f), 20.0f);
            else if (gidx == 2)     res = tanhf(v);
            else                    res = 1.0f / (1.0f + expf(-v));
            gates[(size_t)(bm + rl) * GLD + col] = res;
        }
    }
}

// ---------------- scan phase A: per-chunk summaries -> interleaved float4 ----------------
__global__ __launch_bounds__(256) void scan_a(const float* __restrict__ gates,
                                              float4* __restrict__ s4) {
    int w = blockIdx.x * 4 + (threadIdx.x >> 6);
    int lane = threadIdx.x & 63;
    int b = w >> 8, k = w & (NCHUNK - 1);
    int t0 = k * CLEN;
    const float* gp = gates + ((size_t)(b * SS + t0)) * GLD + lane;
    float Lf = 0.0f, m = -1e30f, c = 0.0f;
    for (int t = 0; t < CLEN; ++t) {
        float li = gp[0], lf = gp[64], z = gp[128];
        gp += GLD;
        Lf += lf;
        float ma = m + lf;
        float mn = fmaxf(ma, li);
        c = expf(ma - mn) * c + expf(li - mn) * z;
        m = mn;
    }
    float4 v; v.x = Lf; v.y = m; v.z = c; v.w = 0.0f;
    s4[(size_t)(b * NCHUNK + k) * 64 + lane] = v;
}

// ---------------- scan phase B: sequential compose, prefetch-16 pipeline ----------------
__global__ __launch_bounds__(64) void scan_b(const float4* __restrict__ s4,
                                             float2* __restrict__ c2) {
    int b = blockIdx.x;
    int n = threadIdx.x;
    size_t base = (size_t)b * NCHUNK * 64 + n;
    float c = 0.0f, m = 0.0f;   // reference init: c0=0, m0=0
    float4 cur[16];
    #pragma unroll
    for (int d = 0; d < 16; ++d) cur[d] = s4[base + (size_t)d * 64];
    for (int kb = 0; kb < NCHUNK; kb += 16) {
        float4 nxt[16];
        if (kb + 16 < NCHUNK) {
            #pragma unroll
            for (int d = 0; d < 16; ++d) nxt[d] = s4[base + (size_t)(kb + 16 + d) * 64];
        }
        #pragma unroll
        for (int d = 0; d < 16; ++d) {
            float2 ci; ci.x = m; ci.y = c;
            c2[base + (size_t)(kb + d) * 64] = ci;
            float4 v = cur[d];
            float ma = m + v.x;
            float mo = fmaxf(ma, v.y);
            c = expf(ma - mo) * c + expf(v.y - mo) * v.z;
            m = mo;
        }
        #pragma unroll
        for (int d = 0; d < 16; ++d) cur[d] = nxt[d];
    }
}

// ---------------- scan phase C: replay chunks, emit h (fp16) ----------------
__global__ __launch_bounds__(256) void scan_c(const float* __restrict__ gates,
                                              const float2* __restrict__ c2,
                                              f16* __restrict__ h) {
    int w = blockIdx.x * 4 + (threadIdx.x >> 6);
    int lane = threadIdx.x & 63;
    int b = w >> 8, k = w & (NCHUNK - 1);
    int t0 = k * CLEN;
    float2 ci = c2[(size_t)(b * NCHUNK + k) * 64 + lane];
    float m = ci.x, c = ci.y;
    const float* gp = gates + ((size_t)(b * SS + t0)) * GLD + lane;
    f16* hp = h + ((size_t)(b * SS + t0)) * NN + lane;
    for (int t = 0; t < CLEN; ++t) {
        float li = gp[0], lf = gp[64], z = gp[128], o = gp[192];
        gp += GLD;
        float ma = m + lf;
        float mn = fmaxf(ma, li);
        c = expf(ma - mn) * c + expf(li - mn) * z;
        m = mn;
        *hp = (f16)(o * tanhf(c));
        hp += NN;
    }
}

// ---------------- output projection: h(32768x64) * Wpf^T(1024x64) + bp -> out ----------------
__global__ __launch_bounds__(256) void out_gemm(const f16* __restrict__ h,
                                                const f16* __restrict__ Wpf,
                                                const float* __restrict__ bp,
                                                float* __restrict__ out) {
    int tid = threadIdx.x, wid = tid >> 6, lane = tid & 63;
    int r0 = (blockIdx.x >> 1) * 32;
    int c0 = (blockIdx.x & 1) * 512 + wid * 128;
    int lrow = lane & 15, lk = (lane >> 4) * 8;

    f32x4 acc[2][8] = {};
    #pragma unroll
    for (int ks = 0; ks < 2; ++ks) {
        int kk = ks * 32;
        f16x8 a[2], bfr[8];
        #pragma unroll
        for (int mf = 0; mf < 2; ++mf)
            a[mf] = *reinterpret_cast<const f16x8*>(h + (size_t)(r0 + mf * 16 + lrow) * NN + kk + lk);
        #pragma unroll
        for (int nf = 0; nf < 8; ++nf)
            bfr[nf] = *reinterpret_cast<const f16x8*>(Wpf + (size_t)(c0 + nf * 16 + lrow) * NN + kk + lk);
        #pragma unroll
        for (int mf = 0; mf < 2; ++mf)
            #pragma unroll
            for (int nf = 0; nf < 8; ++nf)
                acc[mf][nf] = __builtin_amdgcn_mfma_f32_16x16x32_f16(a[mf], bfr[nf], acc[mf][nf], 0, 0, 0);
    }
    int rb = (lane >> 4) * 4;
    #pragma unroll
    for (int nf = 0; nf < 8; ++nf) {
        int col = c0 + nf * 16 + (lane & 15);
        float bias = bp[col];
        #pragma unroll
        for (int mf = 0; mf < 2; ++mf) {
            #pragma unroll
            for (int r = 0; r < 4; ++r) {
                int row = r0 + mf * 16 + rb + r;
                out[(size_t)row * DD + col] = acc[mf][nf][r] + bias;
            }
        }
    }
}

extern "C" void kernel_launch(void* const* d_in, const int* in_sizes, int n_in,
                              void* d_out, int out_size, void* d_ws, size_t ws_size,
                              hipStream_t stream) {
    const float* x    = (const float*)d_in[0];
    const float* ln_w = (const float*)d_in[1];
    const float* ln_b = (const float*)d_in[2];
    const float* Wi   = (const float*)d_in[3];
    const float* bi   = (const float*)d_in[4];
    const float* Wf   = (const float*)d_in[5];
    const float* bfv  = (const float*)d_in[6];
    const float* Wz   = (const float*)d_in[7];
    const float* bz   = (const float*)d_in[8];
    const float* Wo   = (const float*)d_in[9];
    const float* bo   = (const float*)d_in[10];
    const float* Wp   = (const float*)d_in[11];
    const float* bp   = (const float*)d_in[12];
    float* out = (float*)d_out;

    // All scratch in d_ws (~42 MB; ws is ~512 MB). d_out written only by out_gemm.
    char* w = (char*)d_ws;
    float* gates = (float*)w;  w += (size_t)ROWS * GLD * 4;          // 33,554,432
    float4* s4   = (float4*)w; w += (size_t)BB * NCHUNK * 64 * 16;   // 2,097,152
    float2* c2   = (float2*)w; w += (size_t)BB * NCHUNK * 64 * 8;    // 1,048,576
    f16* h       = (f16*)w;    w += (size_t)ROWS * NN * 2;           // 4,194,304
    f16* Wpk     = (f16*)w;    w += 32 * 8192 * 2;                   // 524,288
    f16* Wpf     = (f16*)w;    w += 1024 * 64 * 2;                   // 131,072
    float* ball  = (float*)w;  w += 256 * 4;                         // 1,024
    float* e_all = (float*)w;  w += 256 * 4;                         // 1,024

    prep_all<<<448, 256, 0, stream>>>(Wi, bi, Wf, bfv, Wz, bz, Wo, bo, Wp,
                                      ln_w, ln_b, Wpk, Wpf, ball, e_all);
    gate_gemm<<<1024, 256, 0, stream>>>(x, Wpk, ball, e_all, gates);
    scan_a<<<(BB * NCHUNK) / 4, 256, 0, stream>>>(gates, s4);
    scan_b<<<BB, 64, 0, stream>>>(s4, c2);
    scan_c<<<(BB * NCHUNK) / 4, 256, 0, stream>>>(gates, c2, h);
    out_gemm<<<(ROWS / 32) * 2, 256, 0, stream>>>(h, Wpf, bp, out);
}